// Round 3
// baseline (1623.214 us; speedup 1.0000x reference)
//
#include <hip/hip_runtime.h>
#include <math.h>

#define Bn 4
#define Cn 32
#define Dn 64
#define Hn 64
#define Wn 64
#define PLANE (Hn * Wn)    // 4096
#define DT 16              // d-planes per block
#define LSTRIDE 68         // padded row stride: 68*4 = 272 B = 17*16 (rows 16B-aligned)
#define LROWS 66           // padded rows 0..65 hold data rows -1..64
#define LPLANE (LROWS * LSTRIDE)   // 4488 floats = 17952 B (multiple of 16)

// Exact-grade GELU: 0.5x(1+erf(x/sqrt2)) with A&S 7.1.26 erf (max abs err 1.5e-7).
__device__ __forceinline__ float gelu_exact(float x) {
    float s = fabsf(x) * 0.70710678118654752f;
    float t = __builtin_amdgcn_rcpf(fmaf(0.3275911f, s, 1.0f));
    float P = t * fmaf(t, fmaf(t, fmaf(t, fmaf(t, 1.061405429f, -1.453152027f),
                                       1.421413741f), -0.284496736f), 0.254829592f);
    float E = __builtin_amdgcn_exp2f(-s * s * 1.4426950408889634f);
    float q = P * E;
    float hxq = 0.5f * x * q;
    return x > 0.f ? x - hxq : hxq;
}

__device__ __forceinline__ void read_row(const float* base, float f[10]) {
    float4 a = *(const float4*)(base);       // 16B-aligned (LSTRIDE*4 = 17*16)
    float4 b = *(const float4*)(base + 4);
    float2 c = *(const float2*)(base + 8);
    f[0] = a.x; f[1] = a.y; f[2] = a.z; f[3] = a.w;
    f[4] = b.x; f[5] = b.y; f[6] = b.z; f[7] = b.w;
    f[8] = c.x; f[9] = c.y;
}

__device__ __forceinline__ void acc_row(const float f[10], float w0t, float w1t,
                                        float w2t, float acc[8]) {
#pragma unroll
    for (int j = 0; j < 8; j++) {
        acc[j] = fmaf(f[j],     w0t, acc[j]);
        acc[j] = fmaf(f[j + 1], w1t, acc[j]);
        acc[j] = fmaf(f[j + 2], w2t, acc[j]);
    }
}

// One step: dst = gelu(src + depthwise_conv3x3x3(src)), zero padding.
// 512 threads, (b, c, d0..d0+15). 4-slot LDS ring, 1 barrier/iter,
// register prefetch of plane dz+2, register row-cache of planes dz, dz+1.
// Round-0 structure + Round-0 (tid-linear) mapping (transposed mapping measured
// WORSE: conflicts are intrinsic 2-way aliasing, ~free per m136).
// NEW vs Round 0:
//  - DEFERRED OUTPUT STORE: __syncthreads drains vmcnt(0) incl. stores; Round 0
//    issued 8 stores right before the barrier -> exposed store-ack latency every
//    iter. Now outputs live in regs across the barrier and store at the TOP of
//    the next iter, retiring under that iter's compute.
//  - Vectorized store: 2x dwordx4 instead of 8 scalars.
//  - Unroll-by-2 with C0/C1 NAME SWAP via macro (literal arrays -> SROA-safe,
//    unlike Round 1's by-reference lambda): kills the 30-mov rotate.
__global__ __launch_bounds__(512, 4)
void EmergentSpatialPropagation_step(const float* __restrict__ src,
                                     const float* __restrict__ wgt,
                                     float* __restrict__ dst) {
    __shared__ __align__(16) float lds[4 * LPLANE];   // 71808 B -> 2 blocks/CU

    const int tid = threadIdx.x;
    const int d0  = blockIdx.x * DT;
    const int c   = blockIdx.y;
    const int b   = blockIdx.z;
    const size_t base = ((size_t)(b * Cn + c)) * (size_t)(Dn * PLANE);

    // Zero all 4 slots once; halo cells are never rewritten, stay zero.
    for (int i = tid; i < 4 * LPLANE; i += 512) lds[i] = 0.0f;

    float wt[27];
#pragma unroll
    for (int k = 0; k < 27; k++) wt[k] = wgt[c * 27 + k];   // block-uniform -> SGPR

    const int h  = tid >> 3;          // output row 0..63
    const int w0 = (tid & 7) << 3;    // output col group
    const int m  = tid & 15;          // staging lane role (512 % 16 == 0)

    auto slot = [&](int p) -> float* { return &lds[((p + 1) & 3) * LPLANE]; };

    // Global plane p -> 2 float4 regs (zeros outside volume).
    auto load_g = [&](int p, float4 G[2]) {
        if ((unsigned)p < (unsigned)Dn) {
            const float4* g = (const float4*)(src + base + (size_t)p * PLANE);
            G[0] = g[tid];
            G[1] = g[512 + tid];
        } else {
            G[0] = make_float4(0.f, 0.f, 0.f, 0.f);
            G[1] = make_float4(0.f, 0.f, 0.f, 0.f);
        }
    };

    // Regs -> LDS slot, 16B-aligned writes via shfl repack.
    // Padded group cols 4m..4m+3 hold data cols 4m-1..4m+2 = {prev.w, x, y, z}.
    auto write_plane = [&](int p, const float4 G[2]) {
        float* pl = slot(p);
#pragma unroll
        for (int i = 0; i < 2; i++) {
            int idx = i * 512 + tid;
            int row = (idx >> 4) + 1;                 // padded row 1..64
            float prev = __shfl_up(G[i].w, 1);
            if (m == 0) prev = 0.f;                   // left zero halo
            float4 Wv = make_float4(prev, G[i].x, G[i].y, G[i].z);
            *(float4*)(pl + row * LSTRIDE + 4 * m) = Wv;
            if (m == 15) pl[row * LSTRIDE + 64] = G[i].w;   // data col 63
        }
    };

    // ---- Prologue: stage planes d0-1, d0, d0+1 ----
    __syncthreads();   // zeros visible before staging writes
    {
        float4 Ga[2], Gb[2], Gc[2];
        load_g(d0 - 1, Ga); load_g(d0, Gb); load_g(d0 + 1, Gc);
        write_plane(d0 - 1, Ga); write_plane(d0, Gb); write_plane(d0 + 1, Gc);
    }
    __syncthreads();

    // Register row-cache: C0 = plane dz rows, C1 = plane dz+1 rows.
    float C0[3][10], C1[3][10];
#pragma unroll
    for (int ky = 0; ky < 3; ky++)
        read_row(slot(d0) + (h + ky) * LSTRIDE + w0, C0[ky]);

    // Output of the previous iteration, stored at the TOP of the next one
    // (keeps store-ack latency out of the pre-barrier vmcnt(0) drain).
    float4 so0, so1;
    float* sdptr = nullptr;

#define BODY(IT, CA, CB)                                                        \
    do {                                                                        \
        const int dz = d0 + (IT);                                               \
        float4 G[2];                                                            \
        if ((IT) < DT - 1) load_g(dz + 2, G);   /* prefetch, hidden by FMAs */  \
        if ((IT) > 0) {                         /* deferred store of iter-1 */  \
            *(float4*)(sdptr)     = so0;                                        \
            *(float4*)(sdptr + 4) = so1;                                        \
        }                                                                       \
        _Pragma("unroll")                                                       \
        for (int ky = 0; ky < 3; ky++)          /* fresh plane dz+1 */          \
            read_row(slot(dz + 1) + (h + ky) * LSTRIDE + w0, CB[ky]);           \
        float acc[8] = {0, 0, 0, 0, 0, 0, 0, 0};                                \
        _Pragma("unroll")                                                       \
        for (int ky = 0; ky < 3; ky++) {        /* plane dz-1: LDS, last use */ \
            float T[10];                                                        \
            read_row(slot(dz - 1) + (h + ky) * LSTRIDE + w0, T);                \
            acc_row(T, wt[ky * 3 + 0], wt[ky * 3 + 1], wt[ky * 3 + 2], acc);    \
        }                                                                       \
        _Pragma("unroll")                                                       \
        for (int ky = 0; ky < 3; ky++)          /* plane dz (cached) */         \
            acc_row(CA[ky], wt[9 + ky * 3], wt[9 + ky * 3 + 1],                 \
                    wt[9 + ky * 3 + 2], acc);                                   \
        _Pragma("unroll")                                                       \
        for (int ky = 0; ky < 3; ky++)          /* plane dz+1 (cached) */       \
            acc_row(CB[ky], wt[18 + ky * 3], wt[18 + ky * 3 + 1],               \
                    wt[18 + ky * 3 + 2], acc);                                  \
        sdptr = dst + base + (size_t)dz * PLANE + h * Wn + w0;                  \
        so0 = make_float4(gelu_exact(CA[1][1] + acc[0]),                        \
                          gelu_exact(CA[1][2] + acc[1]),                        \
                          gelu_exact(CA[1][3] + acc[2]),                        \
                          gelu_exact(CA[1][4] + acc[3]));                       \
        so1 = make_float4(gelu_exact(CA[1][5] + acc[4]),                        \
                          gelu_exact(CA[1][6] + acc[5]),                        \
                          gelu_exact(CA[1][7] + acc[6]),                        \
                          gelu_exact(CA[1][8] + acc[7]));                       \
        if ((IT) < DT - 1) {                                                    \
            write_plane(dz + 2, G);   /* slot (dz+3)&3: not read this iter */   \
            __syncthreads();          /* single barrier per iteration */        \
        }                                                                       \
    } while (0)

    // Unroll-by-2 with role name swap: plane dz+1's rows (CB) become next
    // iteration's center plane (CA) with ZERO register copies.
#pragma unroll 1
    for (int it = 0; it < DT; it += 2) {
        BODY(it,     C0, C1);
        BODY(it + 1, C1, C0);
    }
    // Final deferred store.
    *(float4*)(sdptr)     = so0;
    *(float4*)(sdptr + 4) = so1;
#undef BODY
}

extern "C" void kernel_launch(void* const* d_in, const int* in_sizes, int n_in,
                              void* d_out, int out_size, void* d_ws, size_t ws_size,
                              hipStream_t stream) {
    const float* x   = (const float*)d_in[0];
    const float* wgt = (const float*)d_in[1];
    float* out = (float*)d_out;
    float* ws  = (float*)d_ws;

    dim3 grid(Dn / DT, Cn, Bn);   // 4 x 32 x 4 = 512 blocks -> 2/CU resident
    dim3 block(512);

    // 8 steps, ping-pong: in -> ws -> out -> ... -> out
    const float* src = x;
    for (int s = 0; s < 8; s++) {
        float* dst = (s & 1) ? out : ws;
        EmergentSpatialPropagation_step<<<grid, block, 0, stream>>>(src, wgt, dst);
        src = dst;
    }
}

// Round 4
// 798.772 us; speedup vs baseline: 2.0321x; 2.0321x over previous
//
#include <hip/hip_runtime.h>
#include <math.h>

#define Bn 4
#define Cn 32
#define Dn 64
#define Hn 64
#define Wn 64
#define PLANE (Hn * Wn)    // 4096
#define DT 16              // d-planes per block
#define HT 32              // h-rows per block (H split in 2)
#define LSTRIDE 68         // padded row stride: 68*4 = 272 B = 17*16 (rows 16B-aligned)
#define LROWS (HT + 2)     // 34: padded rows 0..33 hold data rows h0-1..h0+32
#define LPLANE (LROWS * LSTRIDE)   // 2312 floats = 9248 B (16B multiple)

// Exact-grade GELU: 0.5x(1+erf(x/sqrt2)) with A&S 7.1.26 erf (max abs err 1.5e-7).
__device__ __forceinline__ float gelu_exact(float x) {
    float s = fabsf(x) * 0.70710678118654752f;
    float t = __builtin_amdgcn_rcpf(fmaf(0.3275911f, s, 1.0f));
    float P = t * fmaf(t, fmaf(t, fmaf(t, fmaf(t, 1.061405429f, -1.453152027f),
                                       1.421413741f), -0.284496736f), 0.254829592f);
    float E = __builtin_amdgcn_exp2f(-s * s * 1.4426950408889634f);
    float q = P * E;
    float hxq = 0.5f * x * q;
    return x > 0.f ? x - hxq : hxq;
}

__device__ __forceinline__ void read_row(const float* base, float f[10]) {
    float4 a = *(const float4*)(base);       // 16B-aligned (LSTRIDE*4 = 17*16)
    float4 b = *(const float4*)(base + 4);
    float2 c = *(const float2*)(base + 8);
    f[0] = a.x; f[1] = a.y; f[2] = a.z; f[3] = a.w;
    f[4] = b.x; f[5] = b.y; f[6] = b.z; f[7] = b.w;
    f[8] = c.x; f[9] = c.y;
}

__device__ __forceinline__ void acc_row(const float f[10], float w0t, float w1t,
                                        float w2t, float acc[8]) {
#pragma unroll
    for (int j = 0; j < 8; j++) {
        acc[j] = fmaf(f[j],     w0t, acc[j]);
        acc[j] = fmaf(f[j + 1], w1t, acc[j]);
        acc[j] = fmaf(f[j + 2], w2t, acc[j]);
    }
}

// One step: dst = gelu(src + depthwise_conv3x3x3(src)), zero padding.
// Round-0 register/cache/barrier structure EXACTLY (the only proven-clean one;
// deferred stores and cache-name rotation both demoted arrays to scratch).
// NEW vs Round 0:
//  - H SPLIT: 256 threads own 32 rows x 64 cols x 16 planes. LDS 4-slot ring
//    shrinks 72 KB -> 37 KB => 4 blocks/CU (grid 1024 = 4 resident/CU).
//    Same 16 waves/CU but 4 independent barrier domains of 4 waves instead of
//    2x8: the per-iter vmcnt(0)+barrier drain now idles only 1/4 of the CU.
//  - h-halo rows (h0-1, h0+32) staged by threads 0..31 (zeros outside volume;
//    written every plane since slots recycle).
//  - Vectorized output store: 2x dwordx4 (wave covers one contiguous 2 KB run).
__global__ __launch_bounds__(256, 4)
void EmergentSpatialPropagation_step(const float* __restrict__ src,
                                     const float* __restrict__ wgt,
                                     float* __restrict__ dst) {
    __shared__ __align__(16) float lds[4 * LPLANE];   // 36992 B -> 4 blocks/CU

    const int tid  = threadIdx.x;
    const int dblk = blockIdx.x >> 1;
    const int hblk = blockIdx.x & 1;
    const int d0   = dblk * DT;
    const int h0   = hblk * HT;
    const int c    = blockIdx.y;
    const int b    = blockIdx.z;
    const size_t base = ((size_t)(b * Cn + c)) * (size_t)(Dn * PLANE);

    // Zero all 4 slots once; cells never rewritten (padded cols 65..67) stay zero.
    for (int i = tid; i < 4 * LPLANE; i += 256) lds[i] = 0.0f;

    float wt[27];
#pragma unroll
    for (int k = 0; k < 27; k++) wt[k] = wgt[c * 27 + k];   // block-uniform -> SGPR

    const int h  = tid >> 3;          // local output row 0..31
    const int w0 = (tid & 7) << 3;    // output col group
    const int m  = tid & 15;          // staging lane role (16 lanes per row)

    auto slot = [&](int p) -> float* { return &lds[((p + 1) & 3) * LPLANE]; };

    // Global plane p -> 2 float4 main regs + 1 float4 halo reg (threads 0..31).
    // Zeros outside the volume (both d- and h-range).
    auto load_g = [&](int p, float4 G[2], float4& GH) {
        GH = make_float4(0.f, 0.f, 0.f, 0.f);
        if ((unsigned)p < (unsigned)Dn) {
            const float4* g = (const float4*)(src + base + (size_t)p * PLANE);
            G[0] = g[h0 * 16 + tid];          // rows h0..h0+15
            G[1] = g[h0 * 16 + 256 + tid];    // rows h0+16..h0+31
            if (tid < 32) {
                int row = (tid < 16) ? (h0 - 1) : (h0 + HT);
                if ((unsigned)row < (unsigned)Hn) GH = g[row * 16 + (tid & 15)];
            }
        } else {
            G[0] = make_float4(0.f, 0.f, 0.f, 0.f);
            G[1] = make_float4(0.f, 0.f, 0.f, 0.f);
        }
    };

    // Regs -> LDS slot, 16B-aligned writes via shfl repack.
    // Padded group cols 4m..4m+3 hold data cols 4m-1..4m+2 = {prev.w, x, y, z}.
    // Halo rows are REWRITTEN every plane (slots recycle; zeros when outside).
    auto write_plane = [&](int p, const float4 G[2], float4 GH) {
        float* pl = slot(p);
#pragma unroll
        for (int i = 0; i < 2; i++) {
            int idx = i * 256 + tid;
            int row = (idx >> 4) + 1;                 // padded row 1..32
            float prev = __shfl_up(G[i].w, 1);
            if (m == 0) prev = 0.f;                   // left zero halo
            float4 Wv = make_float4(prev, G[i].x, G[i].y, G[i].z);
            *(float4*)(pl + row * LSTRIDE + 4 * m) = Wv;
            if (m == 15) pl[row * LSTRIDE + 64] = G[i].w;   // data col 63
        }
        if (tid < 32) {                               // halo rows: padded 0 / 33
            int prow = (tid < 16) ? 0 : (LROWS - 1);
            float prev = __shfl_up(GH.w, 1);          // lanes 0..31 all active
            if (m == 0) prev = 0.f;                   // lane16 is m==0 -> forced 0
            float4 Wv = make_float4(prev, GH.x, GH.y, GH.z);
            *(float4*)(pl + prow * LSTRIDE + 4 * m) = Wv;
            if (m == 15) pl[prow * LSTRIDE + 64] = GH.w;
        }
    };

    // ---- Prologue: stage planes d0-1, d0, d0+1 ----
    __syncthreads();   // zeros visible before staging writes
    {
        float4 Ga[2], Gb[2], Gc[2], Ha, Hb, Hc;
        load_g(d0 - 1, Ga, Ha); load_g(d0, Gb, Hb); load_g(d0 + 1, Gc, Hc);
        write_plane(d0 - 1, Ga, Ha); write_plane(d0, Gb, Hb); write_plane(d0 + 1, Gc, Hc);
    }
    __syncthreads();

    // Register row-cache: C0 = plane dz rows, C1 = plane dz+1 rows.
    float C0[3][10], C1[3][10];
#pragma unroll
    for (int ky = 0; ky < 3; ky++)
        read_row(slot(d0) + (h + ky) * LSTRIDE + w0, C0[ky]);

    for (int it = 0; it < DT; it++) {
        const int dz = d0 + it;

        // Prefetch plane dz+2 into regs (hidden behind compute).
        float4 G[2], GH;
        if (it < DT - 1) load_g(dz + 2, G, GH);

        // Fresh rows of plane dz+1 (written iter-1, visible after barrier).
#pragma unroll
        for (int ky = 0; ky < 3; ky++)
            read_row(slot(dz + 1) + (h + ky) * LSTRIDE + w0, C1[ky]);

        float acc[8] = {0, 0, 0, 0, 0, 0, 0, 0};

        // Plane dz-1 (last use): read from LDS, consume immediately.
#pragma unroll
        for (int ky = 0; ky < 3; ky++) {
            float T[10];
            read_row(slot(dz - 1) + (h + ky) * LSTRIDE + w0, T);
            acc_row(T, wt[ky * 3 + 0], wt[ky * 3 + 1], wt[ky * 3 + 2], acc);
        }
        // Plane dz (cached).
#pragma unroll
        for (int ky = 0; ky < 3; ky++)
            acc_row(C0[ky], wt[9 + ky * 3 + 0], wt[9 + ky * 3 + 1], wt[9 + ky * 3 + 2], acc);
        // Plane dz+1 (cached).
#pragma unroll
        for (int ky = 0; ky < 3; ky++)
            acc_row(C1[ky], wt[18 + ky * 3 + 0], wt[18 + ky * 3 + 1], wt[18 + ky * 3 + 2], acc);

        float* dptr = dst + base + (size_t)dz * PLANE + (h0 + h) * Wn + w0;
        float4 o0 = make_float4(gelu_exact(C0[1][1] + acc[0]),
                                gelu_exact(C0[1][2] + acc[1]),
                                gelu_exact(C0[1][3] + acc[2]),
                                gelu_exact(C0[1][4] + acc[3]));
        float4 o1 = make_float4(gelu_exact(C0[1][5] + acc[4]),
                                gelu_exact(C0[1][6] + acc[5]),
                                gelu_exact(C0[1][7] + acc[6]),
                                gelu_exact(C0[1][8] + acc[7]));
        *(float4*)(dptr)     = o0;      // w0 multiple of 8 -> 32B-aligned
        *(float4*)(dptr + 4) = o1;

        if (it < DT - 1) {
            write_plane(dz + 2, G, GH);   // slot (dz+3)&3: not read this iter
            __syncthreads();              // single barrier per iteration
        }

        // Rotate cache: plane dz+1 becomes next iter's plane dz.
#pragma unroll
        for (int ky = 0; ky < 3; ky++)
#pragma unroll
            for (int k = 0; k < 10; k++) C0[ky][k] = C1[ky][k];
    }
}

extern "C" void kernel_launch(void* const* d_in, const int* in_sizes, int n_in,
                              void* d_out, int out_size, void* d_ws, size_t ws_size,
                              hipStream_t stream) {
    const float* x   = (const float*)d_in[0];
    const float* wgt = (const float*)d_in[1];
    float* out = (float*)d_out;
    float* ws  = (float*)d_ws;

    dim3 grid((Dn / DT) * 2, Cn, Bn);   // (4 d-blks x 2 h-blks) x 32 x 4 = 1024 -> 4/CU
    dim3 block(256);

    // 8 steps, ping-pong: in -> ws -> out -> ... -> out
    const float* src = x;
    for (int s = 0; s < 8; s++) {
        float* dst = (s & 1) ? out : ws;
        EmergentSpatialPropagation_step<<<grid, block, 0, stream>>>(src, wgt, dst);
        src = dst;
    }
}